// Round 6
// baseline (767.791 us; speedup 1.0000x reference)
//
#include <hip/hip_runtime.h>
#include <hip/hip_fp16.h>

constexpr int N    = 100000;
constexpr int E    = 1600000;
constexpr int FIN  = 9;
constexpr int OUTF = 6;
constexpr int G    = 1024;
constexpr int NPB  = 256;                    // nodes per bucket
constexpr int NB   = (N + NPB - 1) / NPB;    // 391 buckets
constexpr int CH   = 2048;                   // edges per chunk
constexpr int NCH  = (E + CH - 1) / CH;      // 782
constexpr int CSRCAP = E + 110000;           // padded csr capacity (int2)

__device__ __forceinline__ void atomAddF(float* p, float v) { unsafeAtomicAdd(p, v); }

// ---- CSR build step 1: bucket histogram (dst>>8) ----
__global__ __launch_bounds__(256) void histB(const int* __restrict__ dst, int* __restrict__ gcnt)
{
    __shared__ int h[NB];
    int t = threadIdx.x;
    for (int i = t; i < NB; i += 256) h[i] = 0;
    __syncthreads();
    int base = blockIdx.x * CH;
#pragma unroll
    for (int i = 0; i < 8; i++) {
        int e = base + i * 256 + t;
        if (e < E) atomicAdd(&h[dst[e] >> 8], 1);
    }
    __syncthreads();
    for (int i = t; i < NB; i += 256) if (h[i]) atomicAdd(&gcnt[i], h[i]);
}

// ---- step 2: scan padded bucket reservations -> bstart + write cursor ----
__global__ __launch_bounds__(512) void scanB(const int* __restrict__ gcnt,
    int* __restrict__ bstart, int* __restrict__ cursor)
{
    __shared__ int sa[512], sb[512];
    int t = threadIdx.x;
    // reservation: room for per-node even-alignment padding (<= +1 per node), kept even
    int v0 = (t < NB) ? ((gcnt[t] + NPB + 1) & ~1) : 0;
    sa[t] = v0;
    __syncthreads();
    int* cur = sa; int* nxt = sb;
    for (int o = 1; o < 512; o <<= 1) {
        int v = cur[t];
        if (t >= o) v += cur[t - o];
        nxt[t] = v;
        __syncthreads();
        int* tmp = cur; cur = nxt; nxt = tmp;
    }
    if (t < NB) { int ex = cur[t] - v0; bstart[t] = ex; cursor[t] = ex; }
}

// ---- step 3: scatter packed edges (src | dloc<<24, w) into bucket-grouped array ----
__global__ __launch_bounds__(256) void passA(const int* __restrict__ src, const int* __restrict__ dst,
    const float* __restrict__ ew, int* __restrict__ cursor, int2* __restrict__ bucketed)
{
    __shared__ int h[NB];
    __shared__ int hb[NB];
    int t = threadIdx.x;
    for (int i = t; i < NB; i += 256) h[i] = 0;
    __syncthreads();
    int base = blockIdx.x * CH;
    int myS[8], myD[8], rk[8]; float myW[8];
#pragma unroll
    for (int i = 0; i < 8; i++) {
        int e = base + i * 256 + t;
        if (e < E) {
            myS[i] = src[e]; myD[i] = dst[e]; myW[i] = ew[e];
            rk[i] = atomicAdd(&h[myD[i] >> 8], 1);
        } else myD[i] = -1;
    }
    __syncthreads();
    for (int i = t; i < NB; i += 256) hb[i] = h[i] ? atomicAdd(&cursor[i], h[i]) : 0;
    __syncthreads();
#pragma unroll
    for (int i = 0; i < 8; i++) if (myD[i] >= 0) {
        int packed = myS[i] | ((myD[i] & 255) << 24);
        bucketed[hb[myD[i] >> 8] + rk[i]] = make_int2(packed, __float_as_int(myW[i]));
    }
}

// ---- step 4: per-bucket local CSR, even-aligned per-node regions + zero pad ----
__global__ __launch_bounds__(NPB) void passB(const int* __restrict__ gcnt, const int* __restrict__ bstart,
    const int2* __restrict__ bucketed, int* __restrict__ ebeg, int* __restrict__ eend,
    int2* __restrict__ csr)
{
    int b = blockIdx.x, t = threadIdx.x;
    int node0 = b * NPB;
    int nnode = min(NPB, N - node0);
    int cnt = gcnt[b], base = bstart[b];
    __shared__ int cl[NPB], sa[NPB], sb[NPB];
    cl[t] = 0;
    __syncthreads();
    for (int e = t; e < cnt; e += NPB) {                 // count only
        int2 r = bucketed[base + e];
        atomicAdd(&cl[((unsigned)r.x) >> 24], 1);
    }
    __syncthreads();
    int deg = cl[t];
    int pc = (deg + 1) & ~1;                             // even-aligned size
    int* cur = sa; int* nxt = sb;
    cur[t] = pc;
    __syncthreads();
    for (int o = 1; o < NPB; o <<= 1) {                  // inclusive scan of padded sizes
        int v = cur[t];
        if (t >= o) v += cur[t - o];
        nxt[t] = v;
        __syncthreads();
        int* tmp = cur; cur = nxt; nxt = tmp;
    }
    int off = cur[t] - pc;                               // exclusive padded offset
    if (t < nnode) { ebeg[node0 + t] = base + off; eend[node0 + t] = base + off + deg; }
    int* cursArr = (cur == sa) ? sb : sa;                // free scan buffer becomes cursor
    cursArr[t] = off;
    __syncthreads();
    for (int e = t; e < cnt; e += NPB) {                 // place
        int2 r = bucketed[base + e];
        int dl = ((unsigned)r.x) >> 24;
        int pos = base + atomicAdd(&cursArr[dl], 1);
        csr[pos] = make_int2(r.x & 0x00FFFFFF, r.y);
    }
    __syncthreads();
    if (t < nnode && (deg & 1)) csr[base + off + deg] = make_int2(0, 0);   // w=0 pad
}

// ---- fused projection: P(fp16) = Ain@Wrel ; Aout = Ain@Wroot + b (Aout may alias Ain) ----
template<int K>
__global__ __launch_bounds__(256) void proj(const float* Ain,
    const float* __restrict__ Wrel, const float* __restrict__ Wroot,
    const float* __restrict__ bias, __half* __restrict__ P, float* Aout)
{
    int t = threadIdx.x, j = t & 63;
    int nl = __builtin_amdgcn_readfirstlane(t >> 6);   // wave-uniform sub-tile
    float wrel[K], wroot[K];
#pragma unroll
    for (int k = 0; k < K; k++) { wrel[k] = Wrel[k * 64 + j]; wroot[k] = Wroot[k * 64 + j]; }
    float bj = bias[j];
    const int ntiles = N / 4;   // exact
    for (int tile = blockIdx.x; tile < ntiles; tile += gridDim.x) {
        int n = tile * 4 + nl;
        float ap = 0.f, ar = bj;
        if constexpr (K == 64) {
            const float4* r4 = (const float4*)(Ain + (size_t)n * 64);
#pragma unroll
            for (int q = 0; q < 16; q++) {
                float4 v = r4[q];
                ap = fmaf(v.x, wrel[4*q+0], ap); ar = fmaf(v.x, wroot[4*q+0], ar);
                ap = fmaf(v.y, wrel[4*q+1], ap); ar = fmaf(v.y, wroot[4*q+1], ar);
                ap = fmaf(v.z, wrel[4*q+2], ap); ar = fmaf(v.z, wroot[4*q+2], ar);
                ap = fmaf(v.w, wrel[4*q+3], ap); ar = fmaf(v.w, wroot[4*q+3], ar);
            }
        } else {
            const float* r = Ain + (size_t)n * K;
#pragma unroll
            for (int k = 0; k < K; k++) {
                float h = r[k];
                ap = fmaf(h, wrel[k], ap);
                ar = fmaf(h, wroot[k], ar);
            }
        }
        P[(size_t)n * 64 + j] = __float2half(ap);
        Aout[(size_t)n * 64 + j] = ar;
    }
}

// ---- gather-aggregate: A[n] += sum_e w_e * P[src_e] ----
// wave per node; lanes 0-31 = even edge, lanes 32-63 = odd edge; each lane
// covers 2 features via uint(half2) loads -> each load instr fetches 2 rows.
template<int EPI>   // 0: write A + BN stats; 1: pool atomics
__global__ __launch_bounds__(256) void gather(const unsigned* __restrict__ P2, float* A,
    const int4* __restrict__ csr4, const int* __restrict__ ebeg, const int* __restrict__ eend,
    float* __restrict__ stats, const int* __restrict__ batch, float* __restrict__ pool)
{
    int t = threadIdx.x, lane = t & 63, hl = lane & 31, hi = lane >> 5, wid = t >> 6;
    int wv = (blockIdx.x * blockDim.x + t) >> 6;
    int nw = (gridDim.x * blockDim.x) >> 6;
    float2 sA = {0.f, 0.f}, sB = {0.f, 0.f};
    for (int n = wv; n < N; n += nw) {
        int beg = ebeg[n], end = eend[n];
        int m = (end - beg + 1) >> 1;                    // int4 (edge-pair) count, pad-safe
        const int4* q = csr4 + (beg >> 1);               // beg even by construction
        float2 a0 = {0.f, 0.f}, a1 = {0.f, 0.f}, a2 = {0.f, 0.f}, a3 = {0.f, 0.f};
        if (hi == 0) a0 = ((const float2*)A)[(size_t)n * 32 + hl];   // root part
        int k = 0;
        for (; k + 4 <= m; k += 4) {
            int4 q0 = q[k], q1 = q[k + 1], q2 = q[k + 2], q3 = q[k + 3];
            int   s0 = hi ? q0.z : q0.x;  float w0 = __int_as_float(hi ? q0.w : q0.y);
            int   s1 = hi ? q1.z : q1.x;  float w1 = __int_as_float(hi ? q1.w : q1.y);
            int   s2 = hi ? q2.z : q2.x;  float w2 = __int_as_float(hi ? q2.w : q2.y);
            int   s3 = hi ? q3.z : q3.x;  float w3 = __int_as_float(hi ? q3.w : q3.y);
            unsigned p0 = P2[(size_t)s0 * 32 + hl];
            unsigned p1 = P2[(size_t)s1 * 32 + hl];
            unsigned p2 = P2[(size_t)s2 * 32 + hl];
            unsigned p3 = P2[(size_t)s3 * 32 + hl];
            float2 f0 = __half22float2(*(__half2*)&p0);
            float2 f1 = __half22float2(*(__half2*)&p1);
            float2 f2 = __half22float2(*(__half2*)&p2);
            float2 f3 = __half22float2(*(__half2*)&p3);
            a0.x = fmaf(w0, f0.x, a0.x); a0.y = fmaf(w0, f0.y, a0.y);
            a1.x = fmaf(w1, f1.x, a1.x); a1.y = fmaf(w1, f1.y, a1.y);
            a2.x = fmaf(w2, f2.x, a2.x); a2.y = fmaf(w2, f2.y, a2.y);
            a3.x = fmaf(w3, f3.x, a3.x); a3.y = fmaf(w3, f3.y, a3.y);
        }
        for (; k < m; k++) {
            int4 q0 = q[k];
            int   s0 = hi ? q0.z : q0.x;  float w0 = __int_as_float(hi ? q0.w : q0.y);
            unsigned p0 = P2[(size_t)s0 * 32 + hl];
            float2 f0 = __half22float2(*(__half2*)&p0);
            a0.x = fmaf(w0, f0.x, a0.x); a0.y = fmaf(w0, f0.y, a0.y);
        }
        float sx = (a0.x + a1.x) + (a2.x + a3.x);
        float sy = (a0.y + a1.y) + (a2.y + a3.y);
        float tx = sx + __shfl(sx, lane ^ 32, 64);       // combine half-waves
        float ty = sy + __shfl(sy, lane ^ 32, 64);
        if constexpr (EPI == 0) {
            if (hi == 0) {
                ((float2*)A)[(size_t)n * 32 + hl] = make_float2(tx, ty);
                sA.x += tx; sA.y += ty;
                sB.x += tx * tx; sB.y += ty * ty;
            }
        } else {
            if (hi == 0) {
                int g = batch[n];
                atomAddF(&pool[g * 64 + 2 * hl], tx);
                atomAddF(&pool[g * 64 + 2 * hl + 1], ty);
            }
        }
    }
    if constexpr (EPI == 0) {
        __shared__ float2 redA[4][32];
        __shared__ float2 redB[4][32];
        if (hi == 0) { redA[wid][hl] = sA; redB[wid][hl] = sB; }
        __syncthreads();
        if (t < 32) {
            float2 v = redA[0][t];
            v.x += redA[1][t].x + redA[2][t].x + redA[3][t].x;
            v.y += redA[1][t].y + redA[2][t].y + redA[3][t].y;
            atomAddF(&stats[2 * t], v.x);
            atomAddF(&stats[2 * t + 1], v.y);
            float2 w = redB[0][t];
            w.x += redB[1][t].x + redB[2][t].x + redB[3][t].x;
            w.y += redB[1][t].y + redB[2][t].y + redB[3][t].y;
            atomAddF(&stats[64 + 2 * t], w.x);
            atomAddF(&stats[64 + 2 * t + 1], w.y);
        }
    }
}

// ---- BN finalize + ReLU, in place, float4 ----
__global__ __launch_bounds__(256) void bn_relu(float4* __restrict__ H4,
    const float* __restrict__ stats, const float* __restrict__ gam, const float* __restrict__ bet)
{
    int i = blockIdx.x * blockDim.x + threadIdx.x;
    constexpr float invN = 1.0f / (float)N;
    int j0 = (i & 15) * 4;
    float4 h = H4[i];
    float r[4] = {h.x, h.y, h.z, h.w};
#pragma unroll
    for (int c = 0; c < 4; c++) {
        int j = j0 + c;
        float m  = stats[j] * invN;
        float vv = stats[64 + j] * invN - m * m;
        float sc = gam[j] * rsqrtf(vv + 1e-5f);
        float sh = bet[j] - m * sc;
        r[c] = fmaxf(fmaf(r[c], sc, sh), 0.f);
    }
    H4[i] = make_float4(r[0], r[1], r[2], r[3]);
}

// ---- head: mean-pool finalize + 2-layer MLP ----
__global__ __launch_bounds__(64) void head(const float* __restrict__ pool,
    const int* __restrict__ batch, const float* __restrict__ Wl1, const float* __restrict__ bl1,
    const float* __restrict__ Wl2, const float* __restrict__ bl2, float* __restrict__ out)
{
    int g = blockIdx.x, t = threadIdx.x;
    __shared__ float sp[64];
    __shared__ float sz[64];
    __shared__ int scnt;
    if (t == 0) {
        int lo = 0, hi = N;
        while (lo < hi) { int m = (lo + hi) >> 1; if (batch[m] < g) lo = m + 1; else hi = m; }
        int lo2 = lo, hi2 = N;
        while (lo2 < hi2) { int m = (lo2 + hi2) >> 1; if (batch[m] < g + 1) lo2 = m + 1; else hi2 = m; }
        scnt = lo2 - lo;
    }
    __syncthreads();
    float cnt = fmaxf((float)scnt, 1.0f);
    sp[t] = pool[g * 64 + t] / cnt;
    __syncthreads();
    float acc = bl1[t];
#pragma unroll
    for (int k = 0; k < 64; k++) acc = fmaf(sp[k], Wl1[k * 64 + t], acc);
    sz[t] = fmaxf(acc, 0.f);
    __syncthreads();
    if (t < OUTF) {
        float o = bl2[t];
#pragma unroll
        for (int k = 0; k < 64; k++) o = fmaf(sz[k], Wl2[k * OUTF + t], o);
        out[g * OUTF + t] = o;
    }
}

extern "C" void kernel_launch(void* const* d_in, const int* in_sizes, int n_in,
                              void* d_out, int out_size, void* d_ws, size_t ws_size,
                              hipStream_t stream)
{
    const float* x     = (const float*)d_in[0];
    const int*   ei    = (const int*)d_in[1];
    const float* ew    = (const float*)d_in[2];
    const int*   batch = (const int*)d_in[3];
    const float* Wrel0 = (const float*)d_in[4];
    const float* Wroot0= (const float*)d_in[5];
    const float* b0    = (const float*)d_in[6];
    const float* Wrel1 = (const float*)d_in[7];
    const float* Wroot1= (const float*)d_in[8];
    const float* b1    = (const float*)d_in[9];
    const float* Wrel2 = (const float*)d_in[10];
    const float* Wroot2= (const float*)d_in[11];
    const float* b2    = (const float*)d_in[12];
    const float* g0    = (const float*)d_in[13];
    const float* be0   = (const float*)d_in[14];
    const float* g1    = (const float*)d_in[15];
    const float* be1   = (const float*)d_in[16];
    const float* Wl1   = (const float*)d_in[17];
    const float* bl1   = (const float*)d_in[18];
    const float* Wl2   = (const float*)d_in[19];
    const float* bl2   = (const float*)d_in[20];
    const int* srcI = ei;
    const int* dstI = ei + E;

    float* ws = (float*)d_ws;
    float*  A      = ws;                               // N*64 f32 (25.6 MB)
    __half* P      = (__half*)(A + (size_t)N * 64);    // N*64 f16 (12.8 MB)
    int2*   csr    = (int2*)(P + (size_t)N * 64);      // CSRCAP int2 (~13.7 MB), 16B-aligned
    int*    ebeg   = (int*)(csr + CSRCAP);             // N
    int*    eend   = ebeg + N;                         // N
    int*    gcnt   = eend + N;                         // NB
    int*    bstart = gcnt + NB;                        // NB
    int*    cursor = bstart + NB;                      // NB
    float*  stats0 = (float*)(cursor + NB);            // 128
    float*  stats1 = stats0 + 128;                     // 128
    float*  pool   = stats1 + 128;                     // G*64
    int2*   bucketed = (int2*)A;                       // E int2 = 12.8MB, aliases A (dead until proj0)

    hipMemsetAsync(gcnt, 0, (size_t)NB * sizeof(int), stream);
    hipMemsetAsync(stats0, 0, (size_t)(256 + G * 64) * sizeof(float), stream);

    // ---- CSR build (bucketed, by dst, pad-aligned) ----
    histB<<<NCH, 256, 0, stream>>>(dstI, gcnt);
    scanB<<<1, 512, 0, stream>>>(gcnt, bstart, cursor);
    passA<<<NCH, 256, 0, stream>>>(srcI, dstI, ew, cursor, bucketed);
    passB<<<NB, NPB, 0, stream>>>(gcnt, bstart, bucketed, ebeg, eend, csr);

    // ---- layer 0 ----
    proj<FIN><<<2048, 256, 0, stream>>>(x, Wrel0, Wroot0, b0, P, A);
    gather<0><<<2048, 256, 0, stream>>>((const unsigned*)P, A, (const int4*)csr, ebeg, eend, stats0, nullptr, nullptr);
    bn_relu<<<N * 16 / 256, 256, 0, stream>>>((float4*)A, stats0, g0, be0);

    // ---- layer 1 ----
    proj<64><<<2048, 256, 0, stream>>>(A, Wrel1, Wroot1, b1, P, A);
    gather<0><<<2048, 256, 0, stream>>>((const unsigned*)P, A, (const int4*)csr, ebeg, eend, stats1, nullptr, nullptr);
    bn_relu<<<N * 16 / 256, 256, 0, stream>>>((float4*)A, stats1, g1, be1);

    // ---- layer 2 + pooling ----
    proj<64><<<2048, 256, 0, stream>>>(A, Wrel2, Wroot2, b2, P, A);
    gather<1><<<2048, 256, 0, stream>>>((const unsigned*)P, A, (const int4*)csr, ebeg, eend, nullptr, batch, pool);

    // ---- head ----
    head<<<G, 64, 0, stream>>>(pool, batch, Wl1, bl1, Wl2, bl2, (float*)d_out);
}

// Round 7
// 652.153 us; speedup vs baseline: 1.1773x; 1.1773x over previous
//
#include <hip/hip_runtime.h>
#include <hip/hip_fp16.h>

constexpr int N    = 100000;
constexpr int E    = 1600000;
constexpr int FIN  = 9;
constexpr int OUTF = 6;
constexpr int G    = 1024;
constexpr int NPB  = 256;                    // nodes per bucket
constexpr int NB   = (N + NPB - 1) / NPB;    // 391 buckets
constexpr int CH   = 2048;                   // edges per chunk
constexpr int NCH  = (E + CH - 1) / CH;      // 782
constexpr int CSRCAP = E + 120000;           // padded csr capacity (int2)

__device__ __forceinline__ void atomAddF(float* p, float v) { unsafeAtomicAdd(p, v); }

// ---- CSR build step 1: bucket histogram (dst>>8) ----
__global__ __launch_bounds__(256) void histB(const int* __restrict__ dst, int* __restrict__ gcnt)
{
    __shared__ int h[NB];
    int t = threadIdx.x;
    for (int i = t; i < NB; i += 256) h[i] = 0;
    __syncthreads();
    int base = blockIdx.x * CH;
#pragma unroll
    for (int i = 0; i < 8; i++) {
        int e = base + i * 256 + t;
        if (e < E) atomicAdd(&h[dst[e] >> 8], 1);
    }
    __syncthreads();
    for (int i = t; i < NB; i += 256) if (h[i]) atomicAdd(&gcnt[i], h[i]);
}

// ---- step 2: scan padded bucket reservations -> bstart + write cursor ----
__global__ __launch_bounds__(512) void scanB(const int* __restrict__ gcnt,
    int* __restrict__ bstart, int* __restrict__ cursor)
{
    __shared__ int sa[512], sb[512];
    int t = threadIdx.x;
    // reservation: per-node even-align padding (<= +1/node) + 8 slack for tail zeros
    int v0 = (t < NB) ? ((gcnt[t] + NPB + 8) & ~1) : 0;
    sa[t] = v0;
    __syncthreads();
    int* cur = sa; int* nxt = sb;
    for (int o = 1; o < 512; o <<= 1) {
        int v = cur[t];
        if (t >= o) v += cur[t - o];
        nxt[t] = v;
        __syncthreads();
        int* tmp = cur; cur = nxt; nxt = tmp;
    }
    if (t < NB) { int ex = cur[t] - v0; bstart[t] = ex; cursor[t] = ex; }
}

// ---- step 3: scatter packed edges (src | dloc<<24, w) into bucket-grouped array ----
__global__ __launch_bounds__(256) void passA(const int* __restrict__ src, const int* __restrict__ dst,
    const float* __restrict__ ew, int* __restrict__ cursor, int2* __restrict__ bucketed)
{
    __shared__ int h[NB];
    __shared__ int hb[NB];
    int t = threadIdx.x;
    for (int i = t; i < NB; i += 256) h[i] = 0;
    __syncthreads();
    int base = blockIdx.x * CH;
    int myS[8], myD[8], rk[8]; float myW[8];
#pragma unroll
    for (int i = 0; i < 8; i++) {
        int e = base + i * 256 + t;
        if (e < E) {
            myS[i] = src[e]; myD[i] = dst[e]; myW[i] = ew[e];
            rk[i] = atomicAdd(&h[myD[i] >> 8], 1);
        } else myD[i] = -1;
    }
    __syncthreads();
    for (int i = t; i < NB; i += 256) hb[i] = h[i] ? atomicAdd(&cursor[i], h[i]) : 0;
    __syncthreads();
#pragma unroll
    for (int i = 0; i < 8; i++) if (myD[i] >= 0) {
        int packed = myS[i] | ((myD[i] & 255) << 24);
        bucketed[hb[myD[i] >> 8] + rk[i]] = make_int2(packed, __float_as_int(myW[i]));
    }
}

// ---- step 4: per-bucket local CSR, even-aligned per-node regions + zero pads ----
__global__ __launch_bounds__(NPB) void passB(const int* __restrict__ gcnt, const int* __restrict__ bstart,
    const int2* __restrict__ bucketed, int* __restrict__ ebeg, int* __restrict__ eend,
    int2* __restrict__ csr)
{
    int b = blockIdx.x, t = threadIdx.x;
    int node0 = b * NPB;
    int nnode = min(NPB, N - node0);
    int cnt = gcnt[b], base = bstart[b];
    __shared__ int cl[NPB], sa[NPB], sb[NPB];
    cl[t] = 0;
    __syncthreads();
    for (int e = t; e < cnt; e += NPB) {                 // count only
        int2 r = bucketed[base + e];
        atomicAdd(&cl[((unsigned)r.x) >> 24], 1);
    }
    __syncthreads();
    int deg = cl[t];
    int pc = (deg + 1) & ~1;                             // even-aligned size
    int* cur = sa; int* nxt = sb;
    cur[t] = pc;
    __syncthreads();
    for (int o = 1; o < NPB; o <<= 1) {                  // inclusive scan of padded sizes
        int v = cur[t];
        if (t >= o) v += cur[t - o];
        nxt[t] = v;
        __syncthreads();
        int* tmp = cur; cur = nxt; nxt = tmp;
    }
    int off = cur[t] - pc;                               // exclusive padded offset
    if (t < nnode) { ebeg[node0 + t] = base + off; eend[node0 + t] = base + off + deg; }
    int* cursArr = (cur == sa) ? sb : sa;                // free scan buffer becomes cursor
    cursArr[t] = off;
    __syncthreads();
    for (int e = t; e < cnt; e += NPB) {                 // place
        int2 r = bucketed[base + e];
        int dl = ((unsigned)r.x) >> 24;
        int pos = base + atomicAdd(&cursArr[dl], 1);
        csr[pos] = make_int2(r.x & 0x00FFFFFF, r.y);
    }
    __syncthreads();
    if (t < nnode && (deg & 1)) csr[base + off + deg] = make_int2(0, 0);   // w=0 pad
    if (t < 4) csr[base + cur[NPB - 1] + t] = make_int2(0, 0);             // bucket tail pads
}

// ---- fused projection: P(fp16) = Ain@Wrel ; Aout = Ain@Wroot + b (Aout may alias Ain) ----
template<int K>
__global__ __launch_bounds__(256) void proj(const float* Ain,
    const float* __restrict__ Wrel, const float* __restrict__ Wroot,
    const float* __restrict__ bias, __half* __restrict__ P, float* Aout)
{
    int t = threadIdx.x, j = t & 63;
    int nl = __builtin_amdgcn_readfirstlane(t >> 6);   // wave-uniform sub-tile
    float wrel[K], wroot[K];
#pragma unroll
    for (int k = 0; k < K; k++) { wrel[k] = Wrel[k * 64 + j]; wroot[k] = Wroot[k * 64 + j]; }
    float bj = bias[j];
    const int ntiles = N / 4;   // exact
    for (int tile = blockIdx.x; tile < ntiles; tile += gridDim.x) {
        int n = tile * 4 + nl;
        float ap = 0.f, ar = bj;
        if constexpr (K == 64) {
            const float4* r4 = (const float4*)(Ain + (size_t)n * 64);
#pragma unroll
            for (int q = 0; q < 16; q++) {
                float4 v = r4[q];
                ap = fmaf(v.x, wrel[4*q+0], ap); ar = fmaf(v.x, wroot[4*q+0], ar);
                ap = fmaf(v.y, wrel[4*q+1], ap); ar = fmaf(v.y, wroot[4*q+1], ar);
                ap = fmaf(v.z, wrel[4*q+2], ap); ar = fmaf(v.z, wroot[4*q+2], ar);
                ap = fmaf(v.w, wrel[4*q+3], ap); ar = fmaf(v.w, wroot[4*q+3], ar);
            }
        } else {
            const float* r = Ain + (size_t)n * K;
#pragma unroll
            for (int k = 0; k < K; k++) {
                float h = r[k];
                ap = fmaf(h, wrel[k], ap);
                ar = fmaf(h, wroot[k], ar);
            }
        }
        P[(size_t)n * 64 + j] = __float2half(ap);
        Aout[(size_t)n * 64 + j] = ar;
    }
}

// ---- gather-aggregate: A[n] += sum_e w_e * P[src_e] ----
// Wave per NODE PAIR: two independent csr streams + accumulator sets so the
// memory pipe always has two dependence chains in flight. Index clamp +
// weight-zeroing keeps the loop branchless (all conditions wave-uniform).
template<int EPI>   // 0: write A + BN stats; 1: pool atomics
__global__ __launch_bounds__(256) void gather(const __half* __restrict__ P, float* A,
    const int2* __restrict__ csr, const int* __restrict__ ebeg, const int* __restrict__ eend,
    float* __restrict__ stats, const int* __restrict__ batch, float* __restrict__ pool)
{
    int t = threadIdx.x, lane = t & 63;
    int wv = (blockIdx.x * blockDim.x + t) >> 6;
    int nw = (gridDim.x * blockDim.x) >> 6;
    float s1 = 0.f, s2 = 0.f;
    const int NPAIR = N / 2;   // N even
    for (int pr = wv; pr < NPAIR; pr += nw) {
        int n0 = 2 * pr, n1 = n0 + 1;
        int b0 = ebeg[n0], m0 = (eend[n0] - b0 + 1) >> 1;   // int4 packet count
        int b1 = ebeg[n1], m1 = (eend[n1] - b1 + 1) >> 1;
        const int4* q0 = (const int4*)csr + (b0 >> 1);      // b0,b1 even by construction
        const int4* q1 = (const int4*)csr + (b1 >> 1);
        int c0 = max(m0 - 1, 0), c1 = max(m1 - 1, 0);
        float x0 = A[(size_t)n0 * 64 + lane];
        float x1 = A[(size_t)n1 * 64 + lane];
        float a0 = 0.f, a1 = 0.f, a2 = 0.f, a3 = 0.f;
        float a4 = 0.f, a5 = 0.f, a6 = 0.f, a7 = 0.f;
        int mm = max(m0, m1);
        for (int k = 0; k < mm; k += 2) {
            int4 qa = q0[min(k,     c0)];
            int4 qb = q0[min(k + 1, c0)];
            int4 qc = q1[min(k,     c1)];
            int4 qd = q1[min(k + 1, c1)];
            float pa0 = __half2float(P[(size_t)qa.x * 64 + lane]);
            float pa1 = __half2float(P[(size_t)qa.z * 64 + lane]);
            float pb0 = __half2float(P[(size_t)qb.x * 64 + lane]);
            float pb1 = __half2float(P[(size_t)qb.z * 64 + lane]);
            float pc0 = __half2float(P[(size_t)qc.x * 64 + lane]);
            float pc1 = __half2float(P[(size_t)qc.z * 64 + lane]);
            float pd0 = __half2float(P[(size_t)qd.x * 64 + lane]);
            float pd1 = __half2float(P[(size_t)qd.z * 64 + lane]);
            float wa = (k     < m0) ? __int_as_float(qa.y) : 0.f;
            float wA = (k     < m0) ? __int_as_float(qa.w) : 0.f;
            float wb = (k + 1 < m0) ? __int_as_float(qb.y) : 0.f;
            float wB = (k + 1 < m0) ? __int_as_float(qb.w) : 0.f;
            float wc = (k     < m1) ? __int_as_float(qc.y) : 0.f;
            float wC = (k     < m1) ? __int_as_float(qc.w) : 0.f;
            float wd = (k + 1 < m1) ? __int_as_float(qd.y) : 0.f;
            float wD = (k + 1 < m1) ? __int_as_float(qd.w) : 0.f;
            a0 = fmaf(wa, pa0, a0); a1 = fmaf(wA, pa1, a1);
            a2 = fmaf(wb, pb0, a2); a3 = fmaf(wB, pb1, a3);
            a4 = fmaf(wc, pc0, a4); a5 = fmaf(wC, pc1, a5);
            a6 = fmaf(wd, pd0, a6); a7 = fmaf(wD, pd1, a7);
        }
        float r0 = x0 + ((a0 + a1) + (a2 + a3));
        float r1 = x1 + ((a4 + a5) + (a6 + a7));
        if constexpr (EPI == 0) {
            A[(size_t)n0 * 64 + lane] = r0;
            A[(size_t)n1 * 64 + lane] = r1;
            s1 += r0 + r1; s2 += r0 * r0 + r1 * r1;
        } else {
            atomAddF(&pool[batch[n0] * 64 + lane], r0);
            atomAddF(&pool[batch[n1] * 64 + lane], r1);
        }
    }
    if constexpr (EPI == 0) {
        __shared__ float sred[256];
        sred[t] = s1; __syncthreads();
        if (t < 64) atomAddF(&stats[t], sred[t] + sred[t+64] + sred[t+128] + sred[t+192]);
        __syncthreads();
        sred[t] = s2; __syncthreads();
        if (t < 64) atomAddF(&stats[64 + t], sred[t] + sred[t+64] + sred[t+128] + sred[t+192]);
    }
}

// ---- BN finalize + ReLU, in place, float4 ----
__global__ __launch_bounds__(256) void bn_relu(float4* __restrict__ H4,
    const float* __restrict__ stats, const float* __restrict__ gam, const float* __restrict__ bet)
{
    int i = blockIdx.x * blockDim.x + threadIdx.x;
    constexpr float invN = 1.0f / (float)N;
    int j0 = (i & 15) * 4;
    float4 h = H4[i];
    float r[4] = {h.x, h.y, h.z, h.w};
#pragma unroll
    for (int c = 0; c < 4; c++) {
        int j = j0 + c;
        float m  = stats[j] * invN;
        float vv = stats[64 + j] * invN - m * m;
        float sc = gam[j] * rsqrtf(vv + 1e-5f);
        float sh = bet[j] - m * sc;
        r[c] = fmaxf(fmaf(r[c], sc, sh), 0.f);
    }
    H4[i] = make_float4(r[0], r[1], r[2], r[3]);
}

// ---- head: mean-pool finalize + 2-layer MLP ----
__global__ __launch_bounds__(64) void head(const float* __restrict__ pool,
    const int* __restrict__ batch, const float* __restrict__ Wl1, const float* __restrict__ bl1,
    const float* __restrict__ Wl2, const float* __restrict__ bl2, float* __restrict__ out)
{
    int g = blockIdx.x, t = threadIdx.x;
    __shared__ float sp[64];
    __shared__ float sz[64];
    __shared__ int scnt;
    if (t == 0) {
        int lo = 0, hi = N;
        while (lo < hi) { int m = (lo + hi) >> 1; if (batch[m] < g) lo = m + 1; else hi = m; }
        int lo2 = lo, hi2 = N;
        while (lo2 < hi2) { int m = (lo2 + hi2) >> 1; if (batch[m] < g + 1) lo2 = m + 1; else hi2 = m; }
        scnt = lo2 - lo;
    }
    __syncthreads();
    float cnt = fmaxf((float)scnt, 1.0f);
    sp[t] = pool[g * 64 + t] / cnt;
    __syncthreads();
    float acc = bl1[t];
#pragma unroll
    for (int k = 0; k < 64; k++) acc = fmaf(sp[k], Wl1[k * 64 + t], acc);
    sz[t] = fmaxf(acc, 0.f);
    __syncthreads();
    if (t < OUTF) {
        float o = bl2[t];
#pragma unroll
        for (int k = 0; k < 64; k++) o = fmaf(sz[k], Wl2[k * OUTF + t], o);
        out[g * OUTF + t] = o;
    }
}

extern "C" void kernel_launch(void* const* d_in, const int* in_sizes, int n_in,
                              void* d_out, int out_size, void* d_ws, size_t ws_size,
                              hipStream_t stream)
{
    const float* x     = (const float*)d_in[0];
    const int*   ei    = (const int*)d_in[1];
    const float* ew    = (const float*)d_in[2];
    const int*   batch = (const int*)d_in[3];
    const float* Wrel0 = (const float*)d_in[4];
    const float* Wroot0= (const float*)d_in[5];
    const float* b0    = (const float*)d_in[6];
    const float* Wrel1 = (const float*)d_in[7];
    const float* Wroot1= (const float*)d_in[8];
    const float* b1    = (const float*)d_in[9];
    const float* Wrel2 = (const float*)d_in[10];
    const float* Wroot2= (const float*)d_in[11];
    const float* b2    = (const float*)d_in[12];
    const float* g0    = (const float*)d_in[13];
    const float* be0   = (const float*)d_in[14];
    const float* g1    = (const float*)d_in[15];
    const float* be1   = (const float*)d_in[16];
    const float* Wl1   = (const float*)d_in[17];
    const float* bl1   = (const float*)d_in[18];
    const float* Wl2   = (const float*)d_in[19];
    const float* bl2   = (const float*)d_in[20];
    const int* srcI = ei;
    const int* dstI = ei + E;

    float* ws = (float*)d_ws;
    float*  A      = ws;                               // N*64 f32 (25.6 MB)
    __half* P      = (__half*)(A + (size_t)N * 64);    // N*64 f16 (12.8 MB)
    int2*   csr    = (int2*)(P + (size_t)N * 64);      // CSRCAP int2 (~13.8 MB), 16B-aligned
    int*    ebeg   = (int*)(csr + CSRCAP);             // N
    int*    eend   = ebeg + N;                         // N
    int*    gcnt   = eend + N;                         // NB
    int*    bstart = gcnt + NB;                        // NB
    int*    cursor = bstart + NB;                      // NB
    float*  stats0 = (float*)(cursor + NB);            // 128
    float*  stats1 = stats0 + 128;                     // 128
    float*  pool   = stats1 + 128;                     // G*64
    int2*   bucketed = (int2*)A;                       // E int2 = 12.8MB, aliases A (dead until proj0)

    hipMemsetAsync(gcnt, 0, (size_t)NB * sizeof(int), stream);
    hipMemsetAsync(stats0, 0, (size_t)(256 + G * 64) * sizeof(float), stream);

    // ---- CSR build (bucketed, by dst, pad-aligned) ----
    histB<<<NCH, 256, 0, stream>>>(dstI, gcnt);
    scanB<<<1, 512, 0, stream>>>(gcnt, bstart, cursor);
    passA<<<NCH, 256, 0, stream>>>(srcI, dstI, ew, cursor, bucketed);
    passB<<<NB, NPB, 0, stream>>>(gcnt, bstart, bucketed, ebeg, eend, csr);

    // ---- layer 0 ----
    proj<FIN><<<2048, 256, 0, stream>>>(x, Wrel0, Wroot0, b0, P, A);
    gather<0><<<2048, 256, 0, stream>>>(P, A, csr, ebeg, eend, stats0, nullptr, nullptr);
    bn_relu<<<N * 16 / 256, 256, 0, stream>>>((float4*)A, stats0, g0, be0);

    // ---- layer 1 ----
    proj<64><<<2048, 256, 0, stream>>>(A, Wrel1, Wroot1, b1, P, A);
    gather<0><<<2048, 256, 0, stream>>>(P, A, csr, ebeg, eend, stats1, nullptr, nullptr);
    bn_relu<<<N * 16 / 256, 256, 0, stream>>>((float4*)A, stats1, g1, be1);

    // ---- layer 2 + pooling ----
    proj<64><<<2048, 256, 0, stream>>>(A, Wrel2, Wroot2, b2, P, A);
    gather<1><<<2048, 256, 0, stream>>>(P, A, csr, ebeg, eend, nullptr, batch, pool);

    // ---- head ----
    head<<<G, 64, 0, stream>>>(pool, batch, Wl1, bl1, Wl2, bl2, (float*)d_out);
}

// Round 8
// 612.838 us; speedup vs baseline: 1.2528x; 1.0642x over previous
//
#include <hip/hip_runtime.h>
#include <hip/hip_fp16.h>

constexpr int N    = 100000;
constexpr int E    = 1600000;
constexpr int FIN  = 9;
constexpr int OUTF = 6;
constexpr int G    = 1024;
constexpr int NPB  = 256;                    // nodes per bucket
constexpr int NB   = (N + NPB - 1) / NPB;    // 391 buckets
constexpr int CH   = 2048;                   // edges per chunk
constexpr int NCH  = (E + CH - 1) / CH;      // 782
constexpr int CSRCAP = E + 120000;           // padded csr capacity (int2)
constexpr int EBUF  = 5888;                  // passB LDS edge stash (Poisson(4096) tail-safe)

__device__ __forceinline__ void atomAddF(float* p, float v) { unsafeAtomicAdd(p, v); }

// ---- CSR build step 1: bucket histogram (dst>>8) ----
__global__ __launch_bounds__(256) void histB(const int* __restrict__ dst, int* __restrict__ gcnt)
{
    __shared__ int h[NB];
    int t = threadIdx.x;
    for (int i = t; i < NB; i += 256) h[i] = 0;
    __syncthreads();
    int base = blockIdx.x * CH;
#pragma unroll
    for (int i = 0; i < 8; i++) {
        int e = base + i * 256 + t;
        if (e < E) atomicAdd(&h[dst[e] >> 8], 1);
    }
    __syncthreads();
    for (int i = t; i < NB; i += 256) if (h[i]) atomicAdd(&gcnt[i], h[i]);
}

// ---- step 2: scan padded bucket reservations -> bstart + write cursor ----
__global__ __launch_bounds__(512) void scanB(const int* __restrict__ gcnt,
    int* __restrict__ bstart, int* __restrict__ cursor)
{
    __shared__ int sa[512], sb[512];
    int t = threadIdx.x;
    int v0 = (t < NB) ? ((gcnt[t] + NPB + 8) & ~1) : 0;
    sa[t] = v0;
    __syncthreads();
    int* cur = sa; int* nxt = sb;
    for (int o = 1; o < 512; o <<= 1) {
        int v = cur[t];
        if (t >= o) v += cur[t - o];
        nxt[t] = v;
        __syncthreads();
        int* tmp = cur; cur = nxt; nxt = tmp;
    }
    if (t < NB) { int ex = cur[t] - v0; bstart[t] = ex; cursor[t] = ex; }
}

// ---- step 3: scatter packed edges (src | dloc<<24, w) into bucket-grouped array ----
__global__ __launch_bounds__(256) void passA(const int* __restrict__ src, const int* __restrict__ dst,
    const float* __restrict__ ew, int* __restrict__ cursor, int2* __restrict__ bucketed)
{
    __shared__ int h[NB];
    __shared__ int hb[NB];
    int t = threadIdx.x;
    for (int i = t; i < NB; i += 256) h[i] = 0;
    __syncthreads();
    int base = blockIdx.x * CH;
    int myS[8], myD[8], rk[8]; float myW[8];
#pragma unroll
    for (int i = 0; i < 8; i++) {
        int e = base + i * 256 + t;
        if (e < E) {
            myS[i] = src[e]; myD[i] = dst[e]; myW[i] = ew[e];
            rk[i] = atomicAdd(&h[myD[i] >> 8], 1);
        } else myD[i] = -1;
    }
    __syncthreads();
    for (int i = t; i < NB; i += 256) hb[i] = h[i] ? atomicAdd(&cursor[i], h[i]) : 0;
    __syncthreads();
#pragma unroll
    for (int i = 0; i < 8; i++) if (myD[i] >= 0) {
        int packed = myS[i] | ((myD[i] & 255) << 24);
        bucketed[hb[myD[i] >> 8] + rk[i]] = make_int2(packed, __float_as_int(myW[i]));
    }
}

// ---- step 4: per-bucket local CSR; edges stashed in LDS (single global read) ----
__global__ __launch_bounds__(NPB) void passB(const int* __restrict__ gcnt, const int* __restrict__ bstart,
    const int2* __restrict__ bucketed, int* __restrict__ ebeg, int* __restrict__ eend,
    int2* __restrict__ csr)
{
    __shared__ int2 ebuf[EBUF];
    __shared__ int cl[NPB], sa[NPB], sb[NPB], curs[NPB];
    int b = blockIdx.x, t = threadIdx.x;
    int node0 = b * NPB;
    int nnode = min(NPB, N - node0);
    int cnt = gcnt[b], base = bstart[b];
    bool fits = (cnt <= EBUF);
    cl[t] = 0;
    __syncthreads();
    for (int e = t; e < cnt; e += NPB) {
        int2 r = bucketed[base + e];
        if (fits) ebuf[e] = r;
        atomicAdd(&cl[((unsigned)r.x) >> 24], 1);
    }
    __syncthreads();
    int deg = cl[t];
    int pc = (deg + 1) & ~1;                             // even-aligned size
    int* cur = sa; int* nxt = sb;
    cur[t] = pc;
    __syncthreads();
    for (int o = 1; o < NPB; o <<= 1) {                  // inclusive scan of padded sizes
        int v = cur[t];
        if (t >= o) v += cur[t - o];
        nxt[t] = v;
        __syncthreads();
        int* tmp = cur; cur = nxt; nxt = tmp;
    }
    int off = cur[t] - pc;
    if (t < nnode) { ebeg[node0 + t] = base + off; eend[node0 + t] = base + off + deg; }
    curs[t] = off;
    __syncthreads();
    for (int e = t; e < cnt; e += NPB) {                 // place
        int2 r = fits ? ebuf[e] : bucketed[base + e];
        int dl = ((unsigned)r.x) >> 24;
        int pos = base + atomicAdd(&curs[dl], 1);
        csr[pos] = make_int2(r.x & 0x00FFFFFF, r.y);
    }
    __syncthreads();
    if (t < nnode && (deg & 1)) csr[base + off + deg] = make_int2(0, 0);   // w=0 pad
    if (t < 4) csr[base + cur[NPB - 1] + t] = make_int2(0, 0);             // bucket tail pads
}

// ---- fused projection: P(fp16) = BNin@Wrel ; Hout(fp16) = BNin@Wroot + b ----
// HIN=0: f32 input (layer 0, x). HIN=1: fp16 input (H), may alias Hout (in-place safe:
// all row loads precede the row's stores via data dependence; rows are wave-private).
template<int K, int HIN>
__global__ __launch_bounds__(256) void proj(const void* Ain_,
    const float* __restrict__ Wrel, const float* __restrict__ Wroot,
    const float* __restrict__ bias, __half* __restrict__ P, __half* Hout)
{
    int t = threadIdx.x, j = t & 63;
    int nl = __builtin_amdgcn_readfirstlane(t >> 6);   // wave-uniform sub-tile
    float wrel[K], wroot[K];
#pragma unroll
    for (int k = 0; k < K; k++) { wrel[k] = Wrel[k * 64 + j]; wroot[k] = Wroot[k * 64 + j]; }
    float bj = bias[j];
    const int ntiles = N / 4;   // exact
    for (int tile = blockIdx.x; tile < ntiles; tile += gridDim.x) {
        int n = tile * 4 + nl;
        float ap = 0.f, ar = bj;
        if constexpr (HIN) {
            const uint4* r4 = (const uint4*)((const __half*)Ain_ + (size_t)n * 64);
#pragma unroll
            for (int q = 0; q < 8; q++) {
                uint4 v = r4[q];
                unsigned arr[4] = {v.x, v.y, v.z, v.w};
#pragma unroll
                for (int c = 0; c < 4; c++) {
                    float2 f = __half22float2(*(const __half2*)&arr[c]);
                    int k = q * 8 + c * 2;
                    ap = fmaf(f.x, wrel[k],     ap); ar = fmaf(f.x, wroot[k],     ar);
                    ap = fmaf(f.y, wrel[k + 1], ap); ar = fmaf(f.y, wroot[k + 1], ar);
                }
            }
        } else {
            const float* r = (const float*)Ain_ + (size_t)n * K;
#pragma unroll
            for (int k = 0; k < K; k++) {
                float h = r[k];
                ap = fmaf(h, wrel[k], ap);
                ar = fmaf(h, wroot[k], ar);
            }
        }
        P[(size_t)n * 64 + j]   = __float2half(ap);
        Hout[(size_t)n * 64 + j] = __float2half(ar);
    }
}

// ---- gather-aggregate: H[n] = root + sum_e w_e * P[src_e]  (R7 structure, fp16 H) ----
template<int EPI>   // 0: write H + BN stats; 1: pool atomics
__global__ __launch_bounds__(256) void gather(const __half* __restrict__ P, __half* H,
    const int2* __restrict__ csr, const int* __restrict__ ebeg, const int* __restrict__ eend,
    float* __restrict__ stats, const int* __restrict__ batch, float* __restrict__ pool)
{
    int t = threadIdx.x, lane = t & 63;
    int wv = (blockIdx.x * blockDim.x + t) >> 6;
    int nw = (gridDim.x * blockDim.x) >> 6;
    float s1 = 0.f, s2 = 0.f;
    const int NPAIR = N / 2;   // N even
    for (int pr = wv; pr < NPAIR; pr += nw) {
        int n0 = 2 * pr, n1 = n0 + 1;
        int b0 = ebeg[n0], m0 = (eend[n0] - b0 + 1) >> 1;   // int4 packet count
        int b1 = ebeg[n1], m1 = (eend[n1] - b1 + 1) >> 1;
        const int4* q0 = (const int4*)csr + (b0 >> 1);      // b0,b1 even by construction
        const int4* q1 = (const int4*)csr + (b1 >> 1);
        int c0 = max(m0 - 1, 0), c1 = max(m1 - 1, 0);
        float x0 = __half2float(H[(size_t)n0 * 64 + lane]);
        float x1 = __half2float(H[(size_t)n1 * 64 + lane]);
        float a0 = 0.f, a1 = 0.f, a2 = 0.f, a3 = 0.f;
        float a4 = 0.f, a5 = 0.f, a6 = 0.f, a7 = 0.f;
        int mm = max(m0, m1);
        for (int k = 0; k < mm; k += 2) {
            int4 qa = q0[min(k,     c0)];
            int4 qb = q0[min(k + 1, c0)];
            int4 qc = q1[min(k,     c1)];
            int4 qd = q1[min(k + 1, c1)];
            float pa0 = __half2float(P[(size_t)qa.x * 64 + lane]);
            float pa1 = __half2float(P[(size_t)qa.z * 64 + lane]);
            float pb0 = __half2float(P[(size_t)qb.x * 64 + lane]);
            float pb1 = __half2float(P[(size_t)qb.z * 64 + lane]);
            float pc0 = __half2float(P[(size_t)qc.x * 64 + lane]);
            float pc1 = __half2float(P[(size_t)qc.z * 64 + lane]);
            float pd0 = __half2float(P[(size_t)qd.x * 64 + lane]);
            float pd1 = __half2float(P[(size_t)qd.z * 64 + lane]);
            float wa = (k     < m0) ? __int_as_float(qa.y) : 0.f;
            float wA = (k     < m0) ? __int_as_float(qa.w) : 0.f;
            float wb = (k + 1 < m0) ? __int_as_float(qb.y) : 0.f;
            float wB = (k + 1 < m0) ? __int_as_float(qb.w) : 0.f;
            float wc = (k     < m1) ? __int_as_float(qc.y) : 0.f;
            float wC = (k     < m1) ? __int_as_float(qc.w) : 0.f;
            float wd = (k + 1 < m1) ? __int_as_float(qd.y) : 0.f;
            float wD = (k + 1 < m1) ? __int_as_float(qd.w) : 0.f;
            a0 = fmaf(wa, pa0, a0); a1 = fmaf(wA, pa1, a1);
            a2 = fmaf(wb, pb0, a2); a3 = fmaf(wB, pb1, a3);
            a4 = fmaf(wc, pc0, a4); a5 = fmaf(wC, pc1, a5);
            a6 = fmaf(wd, pd0, a6); a7 = fmaf(wD, pd1, a7);
        }
        float r0 = x0 + ((a0 + a1) + (a2 + a3));
        float r1 = x1 + ((a4 + a5) + (a6 + a7));
        if constexpr (EPI == 0) {
            H[(size_t)n0 * 64 + lane] = __float2half(r0);
            H[(size_t)n1 * 64 + lane] = __float2half(r1);
            s1 += r0 + r1; s2 += r0 * r0 + r1 * r1;
        } else {
            atomAddF(&pool[batch[n0] * 64 + lane], r0);
            atomAddF(&pool[batch[n1] * 64 + lane], r1);
        }
    }
    if constexpr (EPI == 0) {
        __shared__ float sred[256];
        sred[t] = s1; __syncthreads();
        if (t < 64) atomAddF(&stats[t], sred[t] + sred[t+64] + sred[t+128] + sred[t+192]);
        __syncthreads();
        sred[t] = s2; __syncthreads();
        if (t < 64) atomAddF(&stats[64 + t], sred[t] + sred[t+64] + sred[t+128] + sred[t+192]);
    }
}

// ---- BN finalize + ReLU, in place on fp16 H, 8 halfs/thread ----
__global__ __launch_bounds__(256) void bn_relu(uint4* __restrict__ H4,
    const float* __restrict__ stats, const float* __restrict__ gam, const float* __restrict__ bet)
{
    int i = blockIdx.x * blockDim.x + threadIdx.x;   // over N*8 exactly (800000)
    constexpr float invN = 1.0f / (float)N;
    int j0 = (i & 7) * 8;
    uint4 v = H4[i];
    unsigned arr[4] = {v.x, v.y, v.z, v.w};
#pragma unroll
    for (int c = 0; c < 4; c++) {
        float2 f = __half22float2(*(const __half2*)&arr[c]);
        int j = j0 + 2 * c;
        float m0 = stats[j] * invN,     vv0 = stats[64 + j] * invN - m0 * m0;
        float m1 = stats[j + 1] * invN, vv1 = stats[64 + j + 1] * invN - m1 * m1;
        float sc0 = gam[j] * rsqrtf(vv0 + 1e-5f),     sh0 = bet[j] - m0 * sc0;
        float sc1 = gam[j + 1] * rsqrtf(vv1 + 1e-5f), sh1 = bet[j + 1] - m1 * sc1;
        f.x = fmaxf(fmaf(f.x, sc0, sh0), 0.f);
        f.y = fmaxf(fmaf(f.y, sc1, sh1), 0.f);
        __half2 h = __float22half2_rn(f);
        arr[c] = *(const unsigned*)&h;
    }
    H4[i] = make_uint4(arr[0], arr[1], arr[2], arr[3]);
}

// ---- head: mean-pool finalize + 2-layer MLP ----
__global__ __launch_bounds__(64) void head(const float* __restrict__ pool,
    const int* __restrict__ batch, const float* __restrict__ Wl1, const float* __restrict__ bl1,
    const float* __restrict__ Wl2, const float* __restrict__ bl2, float* __restrict__ out)
{
    int g = blockIdx.x, t = threadIdx.x;
    __shared__ float sp[64];
    __shared__ float sz[64];
    __shared__ int scnt;
    if (t == 0) {
        int lo = 0, hi = N;
        while (lo < hi) { int m = (lo + hi) >> 1; if (batch[m] < g) lo = m + 1; else hi = m; }
        int lo2 = lo, hi2 = N;
        while (lo2 < hi2) { int m = (lo2 + hi2) >> 1; if (batch[m] < g + 1) lo2 = m + 1; else hi2 = m; }
        scnt = lo2 - lo;
    }
    __syncthreads();
    float cnt = fmaxf((float)scnt, 1.0f);
    sp[t] = pool[g * 64 + t] / cnt;
    __syncthreads();
    float acc = bl1[t];
#pragma unroll
    for (int k = 0; k < 64; k++) acc = fmaf(sp[k], Wl1[k * 64 + t], acc);
    sz[t] = fmaxf(acc, 0.f);
    __syncthreads();
    if (t < OUTF) {
        float o = bl2[t];
#pragma unroll
        for (int k = 0; k < 64; k++) o = fmaf(sz[k], Wl2[k * OUTF + t], o);
        out[g * OUTF + t] = o;
    }
}

extern "C" void kernel_launch(void* const* d_in, const int* in_sizes, int n_in,
                              void* d_out, int out_size, void* d_ws, size_t ws_size,
                              hipStream_t stream)
{
    const float* x     = (const float*)d_in[0];
    const int*   ei    = (const int*)d_in[1];
    const float* ew    = (const float*)d_in[2];
    const int*   batch = (const int*)d_in[3];
    const float* Wrel0 = (const float*)d_in[4];
    const float* Wroot0= (const float*)d_in[5];
    const float* b0    = (const float*)d_in[6];
    const float* Wrel1 = (const float*)d_in[7];
    const float* Wroot1= (const float*)d_in[8];
    const float* b1    = (const float*)d_in[9];
    const float* Wrel2 = (const float*)d_in[10];
    const float* Wroot2= (const float*)d_in[11];
    const float* b2    = (const float*)d_in[12];
    const float* g0    = (const float*)d_in[13];
    const float* be0   = (const float*)d_in[14];
    const float* g1    = (const float*)d_in[15];
    const float* be1   = (const float*)d_in[16];
    const float* Wl1   = (const float*)d_in[17];
    const float* bl1   = (const float*)d_in[18];
    const float* Wl2   = (const float*)d_in[19];
    const float* bl2   = (const float*)d_in[20];
    const int* srcI = ei;
    const int* dstI = ei + E;

    __half* H      = (__half*)d_ws;                    // N*64 fp16 (12.8 MB)
    __half* P      = H + (size_t)N * 64;               // N*64 fp16 (12.8 MB)
    int2*   csr    = (int2*)(P + (size_t)N * 64);      // CSRCAP int2 (~13.8 MB), 16B-aligned
    int*    ebeg   = (int*)(csr + CSRCAP);             // N
    int*    eend   = ebeg + N;                         // N
    int*    gcnt   = eend + N;                         // NB   -- zero block starts here
    float*  stats0 = (float*)(gcnt + NB);              // 128
    float*  stats1 = stats0 + 128;                     // 128
    float*  pool   = stats1 + 128;                     // G*64 -- zero block ends here
    int*    bstart = (int*)(pool + G * 64);            // NB
    int*    cursor = bstart + NB;                      // NB
    int2*   bucketed = (int2*)H;                       // E int2 = 12.8MB, aliases H (dead until proj0)

    hipMemsetAsync(gcnt, 0, (size_t)(NB + 256 + G * 64) * sizeof(int), stream);

    // ---- CSR build (bucketed, by dst, pad-aligned) ----
    histB<<<NCH, 256, 0, stream>>>(dstI, gcnt);
    scanB<<<1, 512, 0, stream>>>(gcnt, bstart, cursor);
    passA<<<NCH, 256, 0, stream>>>(srcI, dstI, ew, cursor, bucketed);
    passB<<<NB, NPB, 0, stream>>>(gcnt, bstart, bucketed, ebeg, eend, csr);

    // ---- layer 0 ----
    proj<FIN, 0><<<2048, 256, 0, stream>>>(x, Wrel0, Wroot0, b0, P, H);
    gather<0><<<2048, 256, 0, stream>>>(P, H, csr, ebeg, eend, stats0, nullptr, nullptr);
    bn_relu<<<N * 8 / 256, 256, 0, stream>>>((uint4*)H, stats0, g0, be0);

    // ---- layer 1 ----
    proj<64, 1><<<2048, 256, 0, stream>>>(H, Wrel1, Wroot1, b1, P, H);
    gather<0><<<2048, 256, 0, stream>>>(P, H, csr, ebeg, eend, stats1, nullptr, nullptr);
    bn_relu<<<N * 8 / 256, 256, 0, stream>>>((uint4*)H, stats1, g1, be1);

    // ---- layer 2 + pooling ----
    proj<64, 1><<<2048, 256, 0, stream>>>(H, Wrel2, Wroot2, b2, P, H);
    gather<1><<<2048, 256, 0, stream>>>(P, H, csr, ebeg, eend, nullptr, batch, pool);

    // ---- head ----
    head<<<G, 64, 0, stream>>>(pool, batch, Wl1, bl1, Wl2, bl2, (float*)d_out);
}